// Round 2
// baseline (468.819 us; speedup 1.0000x reference)
//
#include <hip/hip_runtime.h>
#include <cstdint>

// Problem constants (from reference setup_inputs):
//   preds  : (B=16, NC=19, H=512, W=512) float32
//   targets: (B=16, 1024, 1024) int labels in [0,19)  (int64 in ref -> int32 here)
//   grid_size g=16 -> Hc=Wc=32 cells, 16384 cells
// Nearest-neighbor resize: t[b,i,j] = targets[b, 2i, 2j]

#define B_    16
#define NC_   19
#define H_    512
#define W_    512
#define G_    16
#define NCELL 16384                        // B*32*32
#define F4_PER_CELL 1216                   // NC*16*4  (float4 per cell)
#define F4_PER_CH   65536                  // 512*128  (float4 per (b,c) image)
#define INV_TOTAL (1.0f / (float)((long long)B_ * NC_ * H_ * W_))

// One block per grid cell: build presence bitmask from targets, then stream
// the cell's 19x16x16 preds slab computing stable BCE-with-logits.
__global__ __launch_bounds__(256) void fused_kernel(
    const float* __restrict__ preds,
    const int*   __restrict__ targets,
    float*       __restrict__ partial)
{
    const int cell = blockIdx.x;           // b*1024 + ci*32 + cj
    const int tid  = threadIdx.x;
    const int cj = cell & 31;
    const int ci = (cell >> 5) & 31;
    const int b  = cell >> 10;

    // ---- Phase A: presence bitmask (256 labels, one per thread) ----
    const int u = tid >> 4;                // 0..15 within-cell row
    const int v = tid & 15;                // 0..15 within-cell col
    const int row = ((ci << 4) + u) << 1;  // even rows of targets
    const int col = ((cj << 4) + v) << 1;  // even cols
    const int lab = targets[(((b << 10) + row) << 10) + col];
    unsigned m = 1u << lab;

    #pragma unroll
    for (int off = 32; off >= 1; off >>= 1)
        m |= __shfl_xor(m, off, 64);       // wave = 64 lanes

    __shared__ unsigned s_mask;
    if (tid == 0) s_mask = 0u;
    __syncthreads();
    if ((tid & 63) == 0) atomicOr(&s_mask, m);
    __syncthreads();
    const unsigned mask = s_mask;

    // ---- Phase B: BCE over the cell's slab: 19 channels x 16 rows x 4 float4 ----
    // float4 flat index within cell: idx = c*64 + r*4 + q
    // global float4 addr: (b*19 + c)*65536 + (ci*16 + r)*128 + cj*4 + q
    const float4* p4 = (const float4*)preds;
    const int base = (b * NC_) * F4_PER_CH + (ci << 4) * 128 + (cj << 2);

    float acc = 0.0f;
    for (int idx = tid; idx < F4_PER_CELL; idx += 256) {
        const int c = idx >> 6;            // 0..18
        const int r = (idx >> 2) & 15;     // 0..15
        const int q = idx & 3;             // 0..3
        const float4 x = p4[base + c * F4_PER_CH + r * 128 + q];
        const float se = (float)((mask >> c) & 1u);

        // loss = max(x,0) - se*x + log(1 + exp(-|x|))
        float a, t;
        a = fabsf(x.x); t = __logf(1.0f + __expf(-a));
        acc += fmaxf(x.x, 0.0f) - se * x.x + t;
        a = fabsf(x.y); t = __logf(1.0f + __expf(-a));
        acc += fmaxf(x.y, 0.0f) - se * x.y + t;
        a = fabsf(x.z); t = __logf(1.0f + __expf(-a));
        acc += fmaxf(x.z, 0.0f) - se * x.z + t;
        a = fabsf(x.w); t = __logf(1.0f + __expf(-a));
        acc += fmaxf(x.w, 0.0f) - se * x.w + t;
    }

    // ---- block reduction -> partial[cell] (no global atomics) ----
    #pragma unroll
    for (int off = 32; off >= 1; off >>= 1)
        acc += __shfl_down(acc, off, 64);

    __shared__ float s_part[4];
    if ((tid & 63) == 0) s_part[tid >> 6] = acc;
    __syncthreads();
    if (tid == 0)
        partial[cell] = s_part[0] + s_part[1] + s_part[2] + s_part[3];
}

// Single-block final reduction of 16384 partials.
__global__ __launch_bounds__(256) void reduce_kernel(
    const float* __restrict__ partial,
    float*       __restrict__ out)
{
    const int tid = threadIdx.x;
    const float4* p4 = (const float4*)partial;

    float acc = 0.0f;
    for (int i = tid; i < NCELL / 4; i += 256) {   // 4096 float4
        const float4 x = p4[i];
        acc += (x.x + x.y) + (x.z + x.w);
    }

    #pragma unroll
    for (int off = 32; off >= 1; off >>= 1)
        acc += __shfl_down(acc, off, 64);

    __shared__ float s_part[4];
    if ((tid & 63) == 0) s_part[tid >> 6] = acc;
    __syncthreads();
    if (tid == 0)
        out[0] = (s_part[0] + s_part[1] + s_part[2] + s_part[3]) * INV_TOTAL;
}

extern "C" void kernel_launch(void* const* d_in, const int* in_sizes, int n_in,
                              void* d_out, int out_size, void* d_ws, size_t ws_size,
                              hipStream_t stream)
{
    const float* preds   = (const float*)d_in[0];
    const int*   targets = (const int*)d_in[1];
    // d_in[2] is grid_size = 16 (compile-time constant G_)

    float* partial = (float*)d_ws;        // 16384 * 4 B = 64 KB
    float* out     = (float*)d_out;

    fused_kernel<<<NCELL, 256, 0, stream>>>(preds, targets, partial);
    reduce_kernel<<<1, 256, 0, stream>>>(partial, out);
}

// Round 4
// 465.793 us; speedup vs baseline: 1.0065x; 1.0065x over previous
//
#include <hip/hip_runtime.h>
#include <cstdint>

// Problem constants (from reference setup_inputs):
//   preds  : (B=16, NC=19, H=512, W=512) float32
//   targets: (B=16, 1024, 1024) int labels in [0,19)
//   grid_size g=16 -> Hc=Wc=32 cells, 16384 cells
// Nearest-neighbor resize: t[b,i,j] = targets[b, 2i, 2j]

#define B_    16
#define NC_   19
#define H_    512
#define W_    512
#define G_    16
#define NCELL 16384                        // B*32*32
#define W4_   128                          // float4 per row
#define TOTAL4 (B_ * NC_ * H_ * W4_)       // 19,922,944
#define GROUPS (TOTAL4 / 4)                // 4,980,736 groups of 64 B
#define INV_TOTAL (1.0f / (float)((long long)B_ * NC_ * H_ * W_))

// native vector type — accepted by __builtin_nontemporal_load
typedef float vfloat4 __attribute__((ext_vector_type(4)));

// Kernel 1: per-cell class-presence bitmask; one 256-thread block per cell.
// Also zeroes the scalar output (harness poisons d_out to 0xAA each replay).
__global__ __launch_bounds__(256) void presence_kernel(
    const int* __restrict__ targets,
    uint32_t* __restrict__ masks,
    float* __restrict__ out)
{
    const int cell = blockIdx.x;           // b*1024 + ci*32 + cj
    const int tid  = threadIdx.x;
    if (cell == 0 && tid == 0) out[0] = 0.0f;

    const int cj = cell & 31;
    const int ci = (cell >> 5) & 31;
    const int b  = cell >> 10;

    const int u = tid >> 4;                // 0..15 within-cell row
    const int v = tid & 15;                // 0..15 within-cell col
    const int row = ((ci << 4) + u) << 1;  // even rows
    const int col = ((cj << 4) + v) << 1;  // even cols
    const int lab = targets[(((b << 10) + row) << 10) + col];
    unsigned m = 1u << lab;

    #pragma unroll
    for (int off = 32; off >= 1; off >>= 1)
        m |= __shfl_xor(m, off, 64);       // wave = 64 lanes

    __shared__ unsigned s_mask;
    if (tid == 0) s_mask = 0u;
    __syncthreads();
    if ((tid & 63) == 0) atomicOr(&s_mask, m);
    __syncthreads();
    if (tid == 0) masks[cell] = s_mask;
}

// Kernel 2: linear grid-stride BCE sweep. Each thread handles 4 consecutive
// float4 (64 B) per iteration — all 16 floats share one cell column, so one
// mask gather + one index decode per 16 elements. Perfectly coalesced.
__global__ __launch_bounds__(256) void bce_kernel(
    const float* __restrict__ preds,
    const uint32_t* __restrict__ masks,
    float* __restrict__ out)
{
    const int tid     = threadIdx.x;
    const int gidx    = blockIdx.x * 256 + tid;
    const int nthread = gridDim.x * 256;

    const vfloat4* p4 = (const vfloat4*)preds;
    float acc = 0.0f;

    for (int g = gidx; g < GROUPS; g += nthread) {
        const int i4  = g << 2;            // first float4 of the 64 B group
        const int j4  = i4 & (W4_ - 1);    // 0..127
        const int t1  = i4 >> 7;
        const int row = t1 & (H_ - 1);     // 0..511
        const int t2  = t1 >> 9;
        const int c   = t2 % NC_;
        const int b   = t2 / NC_;

        const uint32_t m = masks[(b << 10) + ((row >> 4) << 5) + (j4 >> 2)];
        const float se = (float)((m >> c) & 1u);

        const vfloat4 x0 = __builtin_nontemporal_load(&p4[i4 + 0]);
        const vfloat4 x1 = __builtin_nontemporal_load(&p4[i4 + 1]);
        const vfloat4 x2 = __builtin_nontemporal_load(&p4[i4 + 2]);
        const vfloat4 x3 = __builtin_nontemporal_load(&p4[i4 + 3]);

        // loss = max(x,0) - se*x + log(1+exp(-|x|)); factor se*Σx out.
        float gs = 0.0f;                   // group sum of x
        #define TERM(X)  gs += (X); \
            acc += fmaxf((X), 0.0f) + __logf(1.0f + __expf(-fabsf(X)));
        TERM(x0.x) TERM(x0.y) TERM(x0.z) TERM(x0.w)
        TERM(x1.x) TERM(x1.y) TERM(x1.z) TERM(x1.w)
        TERM(x2.x) TERM(x2.y) TERM(x2.z) TERM(x2.w)
        TERM(x3.x) TERM(x3.y) TERM(x3.z) TERM(x3.w)
        #undef TERM
        acc -= se * gs;
    }

    // wave reduce, then block reduce, then one atomic per block
    #pragma unroll
    for (int off = 32; off >= 1; off >>= 1)
        acc += __shfl_down(acc, off, 64);

    __shared__ float s_part[4];            // 256 threads = 4 waves
    if ((tid & 63) == 0) s_part[tid >> 6] = acc;
    __syncthreads();
    if (tid == 0) {
        const float s = s_part[0] + s_part[1] + s_part[2] + s_part[3];
        atomicAdd(out, s * INV_TOTAL);
    }
}

extern "C" void kernel_launch(void* const* d_in, const int* in_sizes, int n_in,
                              void* d_out, int out_size, void* d_ws, size_t ws_size,
                              hipStream_t stream)
{
    const float* preds   = (const float*)d_in[0];
    const int*   targets = (const int*)d_in[1];
    // d_in[2] is grid_size = 16 (compile-time constant G_)

    uint32_t* masks = (uint32_t*)d_ws;     // 16384 * 4 B = 64 KB
    float*    out   = (float*)d_out;

    presence_kernel<<<NCELL, 256, 0, stream>>>(targets, masks, out);
    bce_kernel<<<4096, 256, 0, stream>>>(preds, masks, out);
}